// Round 1
// 360.854 us; speedup vs baseline: 1.0467x; 1.0467x over previous
//
#include <hip/hip_runtime.h>
#include <stdint.h>

#define DIN 256
#define DOUT 64
#define LMAX 50
#define NEG_INF -1e9f
#define WSTRIDE 264   // bf16 elems per W row in LDS

typedef short bf16x8 __attribute__((ext_vector_type(8)));
typedef float f32x4  __attribute__((ext_vector_type(4)));

static __device__ __forceinline__ unsigned short f2bf(float x) {
    unsigned int u = __float_as_uint(x);
    u += 0x7fffu + ((u >> 16) & 1u);     // RNE
    return (unsigned short)(u >> 16);
}
static __device__ __forceinline__ float bflo(unsigned int u) { return __uint_as_float(u << 16); }
static __device__ __forceinline__ float bfhi(unsigned int u) { return __uint_as_float(u & 0xffff0000u); }

// ---------------------------------------------------------------------------
// Kernel 1: projection via bf16 MFMA 16x16x32 (UNCHANGED — near memory floor:
// 204.8 MB read + 25.6 MB write ~= 37 us at 6.3 TB/s).
// ---------------------------------------------------------------------------
__global__ __launch_bounds__(256) void proj_kernel(
    const float* __restrict__ embed, const float* __restrict__ W,
    unsigned short* __restrict__ ep16, int N)
{
    __shared__ unsigned short wl[64 * WSTRIDE];   // 33,792 B -> 4 blocks/CU

    const int tid  = threadIdx.x;
    const int lane = tid & 63;
    const int wv   = tid >> 6;
    const int mrow = lane & 15;
    const int quad = lane >> 4;

    // ---- one-time W stage: fp32 -> bf16, layout wl[n*264 + k] ----
#pragma unroll
    for (int i = 0; i < 16; ++i) {
        const int idx4 = tid + 256 * i;          // float4 index, coalesced
        const int e    = idx4 * 4;               // element = n*256 + k
        const int n    = e >> 8;
        const int k    = e & 255;
        const float4 f = *(const float4*)&W[e];
        union { unsigned short s[4]; unsigned long long v; } p;
        p.s[0] = f2bf(f.x); p.s[1] = f2bf(f.y);
        p.s[2] = f2bf(f.z); p.s[3] = f2bf(f.w);
        *(unsigned long long*)&wl[n * WSTRIDE + k] = p.v;
    }
    __syncthreads();

    const int m_base = blockIdx.x * 128 + wv * 32;

    f32x4 acc[2][4];
#pragma unroll
    for (int mt = 0; mt < 2; ++mt)
#pragma unroll
        for (int nt = 0; nt < 4; ++nt) acc[mt][nt] = (f32x4){0.f, 0.f, 0.f, 0.f};

    for (int kc = 0; kc < DIN; kc += 32) {
        bf16x8 afrag[2];
#pragma unroll
        for (int mt = 0; mt < 2; ++mt) {
            int row = m_base + mt * 16 + mrow;
            if (row >= N) row = N - 1;                    // clamp; store-guarded
            const float* ap = embed + (size_t)row * DIN + kc + quad * 8;
            const float4 f0 = *(const float4*)ap;
            const float4 f1 = *(const float4*)(ap + 4);
            union { short s[8]; bf16x8 f; } a;
            a.s[0] = (short)f2bf(f0.x); a.s[1] = (short)f2bf(f0.y);
            a.s[2] = (short)f2bf(f0.z); a.s[3] = (short)f2bf(f0.w);
            a.s[4] = (short)f2bf(f1.x); a.s[5] = (short)f2bf(f1.y);
            a.s[6] = (short)f2bf(f1.z); a.s[7] = (short)f2bf(f1.w);
            afrag[mt] = a.f;
        }
#pragma unroll
        for (int nt = 0; nt < 4; ++nt) {
            const bf16x8 bfrag =
                *(const bf16x8*)&wl[(nt * 16 + mrow) * WSTRIDE + kc + quad * 8];
            acc[0][nt] = __builtin_amdgcn_mfma_f32_16x16x32_bf16(
                afrag[0], bfrag, acc[0][nt], 0, 0, 0);
            acc[1][nt] = __builtin_amdgcn_mfma_f32_16x16x32_bf16(
                afrag[1], bfrag, acc[1][nt], 0, 0, 0);
        }
    }

#pragma unroll
    for (int mt = 0; mt < 2; ++mt)
#pragma unroll
        for (int nt = 0; nt < 4; ++nt)
#pragma unroll
            for (int r = 0; r < 4; ++r) {
                const int row = m_base + mt * 16 + quad * 4 + r;
                if (row < N)
                    ep16[(size_t)row * DOUT + nt * 16 + mrow] = f2bf(acc[mt][nt][r]);
            }
}

// ---------------------------------------------------------------------------
// Kernel 2: GAT attention + aggregation.
// NEW this round:
//  * mask compaction — only the nv (~25.5 avg of 50) VALID neighbor rows are
//    DMA'd (ceil(nv/8) width-16 groups + width-4 pairs for the tail; max LDS
//    slot used is 50 so the buffer/occupancy are unchanged: 6 blocks/CU).
//    Cuts DMA instrs 7 -> ~5 avg, LDS-write bytes 6400 -> ~3400 per wave,
//    and phase-2 trip count 25 -> ~13.
//  * __syncthreads removed — fwbuf/attn_s are wave-private, so a per-wave
//    s_waitcnt vmcnt(0) suffices; no cross-wave DMA-drain coupling.
//  * attn_s doubles as the compaction-index scratch (uint bits) before it
//    holds the softmax weights — single type, no aliasing, no LDS growth.
// ---------------------------------------------------------------------------
__global__ __launch_bounds__(256, 6) void agg_kernel(
    const int* __restrict__ neighs, const void* __restrict__ mask,
    const int* __restrict__ dst_idx, const unsigned int* __restrict__ ep16u,
    const float* __restrict__ a_src, const float* __restrict__ a_dst,
    float* __restrict__ out, int B)
{
    __shared__ unsigned int fwbuf[4][LMAX * 32];   // 25,600 B
    __shared__ unsigned int attn_s[4][64];         //  1,024 B (cidx, then attn bits)

    const int tid  = threadIdx.x;
    const int lane = tid & 63;
    const int wv   = tid >> 6;
    const int b    = blockIdx.x * 4 + wv;
    const int bc   = b < B ? b : B - 1;            // clamp (grid exact for B=50000)
    const int c    = lane & 31;

    // mask storage-format detection: flat element 50 (row1,col0) always True.
    const unsigned int* mw = (const unsigned int*)mask;
    const bool byteMode = (mw[12] > 1u);

    // per-lane neighbor mask (lane = l)
    bool mvalid = false;
    if (lane < LMAX) {
        const int mi = bc * LMAX + lane;
        mvalid = byteMode ? (((const uint8_t*)mask)[mi] != 0)
                          : (((const int*)mask)[mi] != 0);
    }
    const unsigned long long vm = __ballot(mvalid);
    const int nv = (int)__popcll(vm);              // >= 1 (mask[:,0] always True)

    const int* nb = neighs + (size_t)bc * LMAX;

    // ---- compact valid neighbor ids into cidx[0..nv) (wave-private LDS) ----
    unsigned int* cidx = attn_s[wv];
    if (mvalid) {
        const int p = (int)__popcll(vm & ((1ull << lane) - 1ull));
        cidx[p] = (unsigned int)nb[lane];
    }
    // same-wave LDS write -> read: LDS pipe is in-order per wave; just stop
    // the compiler from reordering the accesses.
    asm volatile("" ::: "memory");

    // dst row load early (ordinary global load; shares vmcnt FIFO)
    const unsigned int du = ep16u[(size_t)dst_idx[bc] * 32 + c];
    const float2 adv = *(const float2*)&a_dst[2 * c];

    // ---- async gather of COMPACTED rows, chunk-XOR-rotated layout ----
    // stored 16B-chunk sc of LDS slot r holds global chunk sc ^ (r&7)
    unsigned int* buf = fwbuf[wv];
    const int sub    = lane >> 3;                  // 0..7 = slot&7 in full groups
    const int gchunk = (lane & 7) ^ sub;
    const int f      = nv >> 3;                    // full 8-row groups (uniform)
    for (int i = 0; i < f; ++i) {
        const int r = 8 * i + sub;                 // r < nv guaranteed
        const int n = (int)cidx[r];
        const unsigned int* gp = ep16u + (size_t)n * 32 + gchunk * 4;
        __builtin_amdgcn_global_load_lds(
            (const __attribute__((address_space(1))) void*)gp,
            (__attribute__((address_space(3))) void*)&buf[i * 256],
            16, 0, 0);
    }
    // tail: width-4 pairs (2 rows / instr), slots stay <= 50
    const int t     = nv & 7;
    const int npair = (t + 1) >> 1;                // uniform, 0..4
    const int rbase = 8 * f;
    for (int p2 = 0; p2 < npair; ++p2) {
        const int r   = rbase + 2 * p2 + (lane >> 5);
        const int rc  = r < nv ? r : nv - 1;       // duplicate-fill odd tail slot
        const int n   = (int)cidx[rc];
        const int w   = lane & 31;
        const int gwd = (((w >> 2) ^ (r & 7)) << 2) + (w & 3);
        const unsigned int* gp = ep16u + (size_t)n * 32 + gwd;
        __builtin_amdgcn_global_load_lds(
            (const __attribute__((address_space(1))) void*)gp,
            (__attribute__((address_space(3))) void*)&buf[(rbase + 2 * p2) * 32],
            4, 0, 0);
    }

    // ---- dst attention while DMAs fly (halves duplicate; sum = 2x dot) ----
    float pd = bflo(du) * adv.x + bfhi(du) * adv.y;
#pragma unroll
    for (int m = 32; m >= 1; m >>= 1) pd += __shfl_xor(pd, m, 64);
    pd *= 0.5f;
    const float dst_attn = pd >= 0.f ? pd : 0.2f * pd;

    // per-wave DMA drain only — buffers are wave-private, no block barrier
    asm volatile("s_waitcnt vmcnt(0)" ::: "memory");

    // ---- phase 1: uniform k-octets, bank-uniform b128, a_src in SGPRs ----
    const int lc   = lane < nv ? lane : nv - 1;    // clamp: read a valid row
    const int rot7 = lc & 7;
    const unsigned int* fr = buf + lc * 32;
    float dot = 0.f;
#pragma unroll
    for (int k8 = 0; k8 < 8; ++k8) {
        const uint4 u = *(const uint4*)&fr[((k8 ^ rot7) << 2)];
        dot = fmaf(bflo(u.x), a_src[k8 * 8 + 0], dot);
        dot = fmaf(bfhi(u.x), a_src[k8 * 8 + 1], dot);
        dot = fmaf(bflo(u.y), a_src[k8 * 8 + 2], dot);
        dot = fmaf(bfhi(u.y), a_src[k8 * 8 + 3], dot);
        dot = fmaf(bflo(u.z), a_src[k8 * 8 + 4], dot);
        dot = fmaf(bfhi(u.z), a_src[k8 * 8 + 5], dot);
        dot = fmaf(bflo(u.w), a_src[k8 * 8 + 6], dot);
        dot = fmaf(bfhi(u.w), a_src[k8 * 8 + 7], dot);
    }
    const float lr = dot >= 0.f ? dot : 0.2f * dot;
    float s = (lane < nv) ? (dst_attn + lr) : NEG_INF;

    float mx = s;
#pragma unroll
    for (int m = 32; m >= 1; m >>= 1) mx = fmaxf(mx, __shfl_xor(mx, m, 64));
    const float e = __expf(s - mx);                // lanes >= nv -> exactly 0
    float se = e;
#pragma unroll
    for (int m = 32; m >= 1; m >>= 1) se += __shfl_xor(se, m, 64);
    attn_s[wv][lane] = __float_as_uint(e / se);    // overwrites cidx (done with it)
    asm volatile("" ::: "memory");

    // ---- phase 2: only compacted rows; 2 rows/iter, word-rotated b32 reads ----
    const int half = lane >> 5;
    const int nit  = (nv + 1) >> 1;                // uniform trip count
    float acc0 = 0.f, acc1 = 0.f;
    for (int i = 0; i < nit; ++i) {
        const int r  = 2 * i + half;
        const int rr = r < nv ? r : nv - 1;        // clamped read; weight is 0 anyway
        const int sw = (((c >> 2) ^ (rr & 7)) << 2) + (c & 3);
        const unsigned int u = buf[rr * 32 + sw];
        const float w = __uint_as_float(attn_s[wv][r]);
        acc0 = fmaf(w, bflo(u), acc0);
        acc1 = fmaf(w, bfhi(u), acc1);
    }
    acc0 += __shfl_xor(acc0, 32, 64);              // even-rows + odd-rows half
    acc1 += __shfl_xor(acc1, 32, 64);
    if (b < B && lane < 32) {
        float2 o; o.x = acc0; o.y = acc1;
        *(float2*)&out[(size_t)b * DOUT + 2 * c] = o;
    }
}

// ---------------------------------------------------------------------------
extern "C" void kernel_launch(void* const* d_in, const int* in_sizes, int n_in,
                              void* d_out, int out_size, void* d_ws, size_t ws_size,
                              hipStream_t stream)
{
    const int*   neighs  = (const int*)d_in[0];
    const void*  mask    = d_in[1];
    const int*   dst_idx = (const int*)d_in[2];
    const float* embed   = (const float*)d_in[3];
    const float* W       = (const float*)d_in[4];
    const float* a_src   = (const float*)d_in[5];
    const float* a_dst   = (const float*)d_in[6];
    float* out = (float*)d_out;

    const int B = in_sizes[2];            // 50000
    const int N = in_sizes[3] / DIN;      // 200000

    unsigned short* ep16 = (unsigned short*)d_ws;   // N*64*2 = 25.6 MB

    proj_kernel<<<dim3((N + 127) / 128), dim3(256), 0, stream>>>(embed, W, ep16, N);
    agg_kernel<<<dim3((B + 3) / 4), dim3(256), 0, stream>>>(
        neighs, mask, dst_idx, (const unsigned int*)ep16, a_src, a_dst, out, B);
}

// Round 2
// 359.019 us; speedup vs baseline: 1.0520x; 1.0051x over previous
//
#include <hip/hip_runtime.h>
#include <stdint.h>

#define DIN 256
#define DOUT 64
#define LMAX 50
#define NEG_INF -1e9f
#define WSTRIDE 264   // bf16 elems per W row in LDS

typedef short bf16x8 __attribute__((ext_vector_type(8)));
typedef float f32x4  __attribute__((ext_vector_type(4)));

static __device__ __forceinline__ unsigned short f2bf(float x) {
    unsigned int u = __float_as_uint(x);
    u += 0x7fffu + ((u >> 16) & 1u);     // RNE
    return (unsigned short)(u >> 16);
}
static __device__ __forceinline__ float bflo(unsigned int u) { return __uint_as_float(u << 16); }
static __device__ __forceinline__ float bfhi(unsigned int u) { return __uint_as_float(u & 0xffff0000u); }

// ---------------------------------------------------------------------------
// Kernel 1: projection via bf16 MFMA 16x16x32 (UNCHANGED — near memory floor:
// 204.8 MB read + 25.6 MB write ~= 37 us at 6.3 TB/s).
// ---------------------------------------------------------------------------
__global__ __launch_bounds__(256) void proj_kernel(
    const float* __restrict__ embed, const float* __restrict__ W,
    unsigned short* __restrict__ ep16, int N)
{
    __shared__ unsigned short wl[64 * WSTRIDE];   // 33,792 B -> 4 blocks/CU

    const int tid  = threadIdx.x;
    const int lane = tid & 63;
    const int wv   = tid >> 6;
    const int mrow = lane & 15;
    const int quad = lane >> 4;

    // ---- one-time W stage: fp32 -> bf16, layout wl[n*264 + k] ----
#pragma unroll
    for (int i = 0; i < 16; ++i) {
        const int idx4 = tid + 256 * i;          // float4 index, coalesced
        const int e    = idx4 * 4;               // element = n*256 + k
        const int n    = e >> 8;
        const int k    = e & 255;
        const float4 f = *(const float4*)&W[e];
        union { unsigned short s[4]; unsigned long long v; } p;
        p.s[0] = f2bf(f.x); p.s[1] = f2bf(f.y);
        p.s[2] = f2bf(f.z); p.s[3] = f2bf(f.w);
        *(unsigned long long*)&wl[n * WSTRIDE + k] = p.v;
    }
    __syncthreads();

    const int m_base = blockIdx.x * 128 + wv * 32;

    f32x4 acc[2][4];
#pragma unroll
    for (int mt = 0; mt < 2; ++mt)
#pragma unroll
        for (int nt = 0; nt < 4; ++nt) acc[mt][nt] = (f32x4){0.f, 0.f, 0.f, 0.f};

    for (int kc = 0; kc < DIN; kc += 32) {
        bf16x8 afrag[2];
#pragma unroll
        for (int mt = 0; mt < 2; ++mt) {
            int row = m_base + mt * 16 + mrow;
            if (row >= N) row = N - 1;                    // clamp; store-guarded
            const float* ap = embed + (size_t)row * DIN + kc + quad * 8;
            const float4 f0 = *(const float4*)ap;
            const float4 f1 = *(const float4*)(ap + 4);
            union { short s[8]; bf16x8 f; } a;
            a.s[0] = (short)f2bf(f0.x); a.s[1] = (short)f2bf(f0.y);
            a.s[2] = (short)f2bf(f0.z); a.s[3] = (short)f2bf(f0.w);
            a.s[4] = (short)f2bf(f1.x); a.s[5] = (short)f2bf(f1.y);
            a.s[6] = (short)f2bf(f1.z); a.s[7] = (short)f2bf(f1.w);
            afrag[mt] = a.f;
        }
#pragma unroll
        for (int nt = 0; nt < 4; ++nt) {
            const bf16x8 bfrag =
                *(const bf16x8*)&wl[(nt * 16 + mrow) * WSTRIDE + kc + quad * 8];
            acc[0][nt] = __builtin_amdgcn_mfma_f32_16x16x32_bf16(
                afrag[0], bfrag, acc[0][nt], 0, 0, 0);
            acc[1][nt] = __builtin_amdgcn_mfma_f32_16x16x32_bf16(
                afrag[1], bfrag, acc[1][nt], 0, 0, 0);
        }
    }

#pragma unroll
    for (int mt = 0; mt < 2; ++mt)
#pragma unroll
        for (int nt = 0; nt < 4; ++nt)
#pragma unroll
            for (int r = 0; r < 4; ++r) {
                const int row = m_base + mt * 16 + quad * 4 + r;
                if (row < N)
                    ep16[(size_t)row * DOUT + nt * 16 + mrow] = f2bf(acc[mt][nt][r]);
            }
}

// ---------------------------------------------------------------------------
// Kernel 2: GAT attention + aggregation.
// NEW this round:
//  * dst-attention path DELETED. edge = LR(dst.a_dst) + LR(neigh.a_src); the
//    dst term is constant over the softmax axis -> softmax(c+x) = softmax(x).
//    Removes a 2-chained global load (dst_idx -> du gather, ~1200 cyc) that
//    shared the vmcnt FIFO with the neighbor DMAs (it was likely the drain's
//    critical path), plus a 6-level shuffle reduce and 6.6 MB of traffic.
//    Exact under max-subtracted softmax (shift cancels pre-exp).
//  * LDS cidx round-trip -> ds_permute_b32 register compaction. Valid lane l
//    pushes nb[l] to rank p; invalid lanes push to unique slots nv+(l-p)
//    (bijection on 0..63, no collisions). DMA loop fetches indices by __shfl.
//  * softmax weights kept in registers (lane r holds w_r); phase 2 reads them
//    via __shfl broadcast. attn_s LDS array + both fences deleted.
// ---------------------------------------------------------------------------
__global__ __launch_bounds__(256, 6) void agg_kernel(
    const int* __restrict__ neighs, const void* __restrict__ mask,
    const unsigned int* __restrict__ ep16u,
    const float* __restrict__ a_src,
    float* __restrict__ out, int B)
{
    __shared__ unsigned int fwbuf[4][LMAX * 32];   // 25,600 B -> 6 blocks/CU

    const int tid  = threadIdx.x;
    const int lane = tid & 63;
    const int wv   = tid >> 6;
    const int b    = blockIdx.x * 4 + wv;
    const int bc   = b < B ? b : B - 1;            // clamp (grid exact for B=50000)
    const int c    = lane & 31;

    // mask storage-format detection: flat element 50 (row1,col0) always True.
    const unsigned int* mw = (const unsigned int*)mask;
    const bool byteMode = (mw[12] > 1u);

    // per-lane neighbor mask (lane = l) + neighbor id
    const int* nb = neighs + (size_t)bc * LMAX;
    bool mvalid = false;
    int  nbv    = 0;
    if (lane < LMAX) {
        const int mi = bc * LMAX + lane;
        mvalid = byteMode ? (((const uint8_t*)mask)[mi] != 0)
                          : (((const int*)mask)[mi] != 0);
        nbv = nb[lane];
    }
    const unsigned long long vm = __ballot(mvalid);
    const int nv = (int)__popcll(vm);              // >= 1 (mask[:,0] always True)

    // ---- register compaction via ds_permute push ----
    // valid lane l -> rank p; invalid lane l -> nv + (#invalid below l).
    // This is a bijection on lanes 0..63: no collisions, every lane receives.
    const int p    = (int)__popcll(vm & ((1ull << lane) - 1ull));
    const int dsta = mvalid ? p : (nv + (lane - p));
    const int cnb  = __builtin_amdgcn_ds_permute(dsta << 2, nbv);
    // lane r (r < nv) now holds the r-th valid neighbor id in a register.

    // ---- async gather of compacted rows, chunk-XOR-rotated layout ----
    // stored 16B-chunk sc of LDS slot r holds global chunk sc ^ (r&7)
    unsigned int* buf = fwbuf[wv];
    const int sub    = lane >> 3;                  // 0..7 = slot&7 in full groups
    const int gchunk = (lane & 7) ^ sub;
    const int f      = nv >> 3;                    // full 8-row groups (uniform)
    for (int i = 0; i < f; ++i) {
        const int r = 8 * i + sub;                 // r < nv guaranteed
        const int n = __shfl(cnb, r, 64);
        const unsigned int* gp = ep16u + (size_t)n * 32 + gchunk * 4;
        __builtin_amdgcn_global_load_lds(
            (const __attribute__((address_space(1))) void*)gp,
            (__attribute__((address_space(3))) void*)&buf[i * 256],
            16, 0, 0);
    }
    // tail: width-4 pairs (2 rows / instr), slots stay <= 50
    const int t     = nv & 7;
    const int npair = (t + 1) >> 1;                // uniform, 0..4
    const int rbase = 8 * f;
    for (int p2 = 0; p2 < npair; ++p2) {
        const int r   = rbase + 2 * p2 + (lane >> 5);
        const int rc  = r < nv ? r : nv - 1;       // duplicate-fill odd tail slot
        const int n   = __shfl(cnb, rc, 64);
        const int w   = lane & 31;
        const int gwd = (((w >> 2) ^ (r & 7)) << 2) + (w & 3);
        const unsigned int* gp = ep16u + (size_t)n * 32 + gwd;
        __builtin_amdgcn_global_load_lds(
            (const __attribute__((address_space(1))) void*)gp,
            (__attribute__((address_space(3))) void*)&buf[(rbase + 2 * p2) * 32],
            4, 0, 0);
    }

    // per-wave DMA drain only — buffers are wave-private, no block barrier
    asm volatile("s_waitcnt vmcnt(0)" ::: "memory");

    // ---- phase 1: uniform k-octets, bank-uniform b128, a_src in SGPRs ----
    const int lc   = lane < nv ? lane : nv - 1;    // clamp: read a valid row
    const int rot7 = lc & 7;
    const unsigned int* fr = buf + lc * 32;
    float dot = 0.f;
#pragma unroll
    for (int k8 = 0; k8 < 8; ++k8) {
        const uint4 u = *(const uint4*)&fr[((k8 ^ rot7) << 2)];
        dot = fmaf(bflo(u.x), a_src[k8 * 8 + 0], dot);
        dot = fmaf(bfhi(u.x), a_src[k8 * 8 + 1], dot);
        dot = fmaf(bflo(u.y), a_src[k8 * 8 + 2], dot);
        dot = fmaf(bfhi(u.y), a_src[k8 * 8 + 3], dot);
        dot = fmaf(bflo(u.z), a_src[k8 * 8 + 4], dot);
        dot = fmaf(bfhi(u.z), a_src[k8 * 8 + 5], dot);
        dot = fmaf(bflo(u.w), a_src[k8 * 8 + 6], dot);
        dot = fmaf(bfhi(u.w), a_src[k8 * 8 + 7], dot);
    }
    const float lr = dot >= 0.f ? dot : 0.2f * dot;
    float s = (lane < nv) ? lr : NEG_INF;

    float mx = s;
#pragma unroll
    for (int m = 32; m >= 1; m >>= 1) mx = fmaxf(mx, __shfl_xor(mx, m, 64));
    const float e = __expf(s - mx);                // lanes >= nv -> exactly 0
    float se = e;
#pragma unroll
    for (int m = 32; m >= 1; m >>= 1) se += __shfl_xor(se, m, 64);
    const float attn = e / se;                     // lane r holds weight w_r

    // ---- phase 2: 2 rows/iter, word-rotated b32 reads, shfl-broadcast w ----
    const int half = lane >> 5;
    const int nit  = (nv + 1) >> 1;                // uniform trip count
    float acc0 = 0.f, acc1 = 0.f;
    for (int i = 0; i < nit; ++i) {
        const int r  = 2 * i + half;
        const int rr = r < nv ? r : nv - 1;        // clamped row read (w=0 there,
                                                   // but slot >= nv is poison: 0*NaN!)
        const float w = __shfl(attn, r, 64);       // r <= 50 < 64; lane nv holds 0
        const int sw = (((c >> 2) ^ (rr & 7)) << 2) + (c & 3);
        const unsigned int u = buf[rr * 32 + sw];
        acc0 = fmaf(w, bflo(u), acc0);
        acc1 = fmaf(w, bfhi(u), acc1);
    }
    acc0 += __shfl_xor(acc0, 32, 64);              // even-rows + odd-rows half
    acc1 += __shfl_xor(acc1, 32, 64);
    if (b < B && lane < 32) {
        float2 o; o.x = acc0; o.y = acc1;
        *(float2*)&out[(size_t)b * DOUT + 2 * c] = o;
    }
}

// ---------------------------------------------------------------------------
extern "C" void kernel_launch(void* const* d_in, const int* in_sizes, int n_in,
                              void* d_out, int out_size, void* d_ws, size_t ws_size,
                              hipStream_t stream)
{
    const int*   neighs  = (const int*)d_in[0];
    const void*  mask    = d_in[1];
    const float* embed   = (const float*)d_in[3];
    const float* W       = (const float*)d_in[4];
    const float* a_src   = (const float*)d_in[5];
    float* out = (float*)d_out;

    const int B = in_sizes[2];            // 50000
    const int N = in_sizes[3] / DIN;      // 200000

    unsigned short* ep16 = (unsigned short*)d_ws;   // N*64*2 = 25.6 MB

    proj_kernel<<<dim3((N + 127) / 128), dim3(256), 0, stream>>>(embed, W, ep16, N);
    agg_kernel<<<dim3((B + 3) / 4), dim3(256), 0, stream>>>(
        neighs, mask, (const unsigned int*)ep16, a_src, out, B);
}

// Round 3
// 357.498 us; speedup vs baseline: 1.0565x; 1.0043x over previous
//
#include <hip/hip_runtime.h>
#include <stdint.h>

#define DIN 256
#define DOUT 64
#define LMAX 50
#define NEG_INF -1e9f
#define WSTRIDE 264   // bf16 elems per W row in LDS

typedef short bf16x8 __attribute__((ext_vector_type(8)));
typedef float f32x4  __attribute__((ext_vector_type(4)));

static __device__ __forceinline__ unsigned short f2bf(float x) {
    unsigned int u = __float_as_uint(x);
    u += 0x7fffu + ((u >> 16) & 1u);     // RNE
    return (unsigned short)(u >> 16);
}
static __device__ __forceinline__ float bflo(unsigned int u) { return __uint_as_float(u << 16); }
static __device__ __forceinline__ float bfhi(unsigned int u) { return __uint_as_float(u & 0xffff0000u); }

// ---------------------------------------------------------------------------
// Kernel 1: projection via bf16 MFMA 16x16x32 (UNCHANGED — near memory floor:
// 204.8 MB read + 25.6 MB write ~= 37 us at 6.3 TB/s).
// ---------------------------------------------------------------------------
__global__ __launch_bounds__(256) void proj_kernel(
    const float* __restrict__ embed, const float* __restrict__ W,
    unsigned short* __restrict__ ep16, int N)
{
    __shared__ unsigned short wl[64 * WSTRIDE];   // 33,792 B -> 4 blocks/CU

    const int tid  = threadIdx.x;
    const int lane = tid & 63;
    const int wv   = tid >> 6;
    const int mrow = lane & 15;
    const int quad = lane >> 4;

    // ---- one-time W stage: fp32 -> bf16, layout wl[n*264 + k] ----
#pragma unroll
    for (int i = 0; i < 16; ++i) {
        const int idx4 = tid + 256 * i;          // float4 index, coalesced
        const int e    = idx4 * 4;               // element = n*256 + k
        const int n    = e >> 8;
        const int k    = e & 255;
        const float4 f = *(const float4*)&W[e];
        union { unsigned short s[4]; unsigned long long v; } p;
        p.s[0] = f2bf(f.x); p.s[1] = f2bf(f.y);
        p.s[2] = f2bf(f.z); p.s[3] = f2bf(f.w);
        *(unsigned long long*)&wl[n * WSTRIDE + k] = p.v;
    }
    __syncthreads();

    const int m_base = blockIdx.x * 128 + wv * 32;

    f32x4 acc[2][4];
#pragma unroll
    for (int mt = 0; mt < 2; ++mt)
#pragma unroll
        for (int nt = 0; nt < 4; ++nt) acc[mt][nt] = (f32x4){0.f, 0.f, 0.f, 0.f};

    for (int kc = 0; kc < DIN; kc += 32) {
        bf16x8 afrag[2];
#pragma unroll
        for (int mt = 0; mt < 2; ++mt) {
            int row = m_base + mt * 16 + mrow;
            if (row >= N) row = N - 1;                    // clamp; store-guarded
            const float* ap = embed + (size_t)row * DIN + kc + quad * 8;
            const float4 f0 = *(const float4*)ap;
            const float4 f1 = *(const float4*)(ap + 4);
            union { short s[8]; bf16x8 f; } a;
            a.s[0] = (short)f2bf(f0.x); a.s[1] = (short)f2bf(f0.y);
            a.s[2] = (short)f2bf(f0.z); a.s[3] = (short)f2bf(f0.w);
            a.s[4] = (short)f2bf(f1.x); a.s[5] = (short)f2bf(f1.y);
            a.s[6] = (short)f2bf(f1.z); a.s[7] = (short)f2bf(f1.w);
            afrag[mt] = a.f;
        }
#pragma unroll
        for (int nt = 0; nt < 4; ++nt) {
            const bf16x8 bfrag =
                *(const bf16x8*)&wl[(nt * 16 + mrow) * WSTRIDE + kc + quad * 8];
            acc[0][nt] = __builtin_amdgcn_mfma_f32_16x16x32_bf16(
                afrag[0], bfrag, acc[0][nt], 0, 0, 0);
            acc[1][nt] = __builtin_amdgcn_mfma_f32_16x16x32_bf16(
                afrag[1], bfrag, acc[1][nt], 0, 0, 0);
        }
    }

#pragma unroll
    for (int mt = 0; mt < 2; ++mt)
#pragma unroll
        for (int nt = 0; nt < 4; ++nt)
#pragma unroll
            for (int r = 0; r < 4; ++r) {
                const int row = m_base + mt * 16 + quad * 4 + r;
                if (row < N)
                    ep16[(size_t)row * DOUT + nt * 16 + mrow] = f2bf(acc[mt][nt][r]);
            }
}

// ---------------------------------------------------------------------------
// Kernel 2: GAT attention + aggregation.
// NEW this round (phase 2 only; everything else held fixed):
//  * b128 chunk-per-lane aggregation — lane l owns global chunk gc=l&7
//    (cols 8gc..8gc+7) and sub-slot s8=l>>3; one ds_read_b128 per iteration
//    covers 8 rows x 64 cols (the 64 lane addresses tile the 1KB row-group
//    exactly -> conflict-free). Weight = one shfl per lane per iter.
//    13 dependent b32-pair iterations -> ~4 b128 iterations.
//  * software-pipelined (prefetch distance 1): next iter's ds_read + shfl
//    issue before current iter's 16 unpack+fmaf, hiding LDS latency in the
//    runtime-trip-count loop the compiler can't unroll.
//  * epilogue: 3-level shfl_xor (8/16/32) reduce over same-chunk lanes;
//    lanes 0..7 store 2x float4 (256B contiguous).
// ---------------------------------------------------------------------------
__global__ __launch_bounds__(256, 6) void agg_kernel(
    const int* __restrict__ neighs, const void* __restrict__ mask,
    const unsigned int* __restrict__ ep16u,
    const float* __restrict__ a_src,
    float* __restrict__ out, int B)
{
    __shared__ unsigned int fwbuf[4][LMAX * 32];   // 25,600 B -> 6 blocks/CU

    const int tid  = threadIdx.x;
    const int lane = tid & 63;
    const int wv   = tid >> 6;
    const int b    = blockIdx.x * 4 + wv;
    const int bc   = b < B ? b : B - 1;            // clamp (grid exact for B=50000)

    // mask storage-format detection: flat element 50 (row1,col0) always True.
    const unsigned int* mw = (const unsigned int*)mask;
    const bool byteMode = (mw[12] > 1u);

    // per-lane neighbor mask (lane = l) + neighbor id
    const int* nb = neighs + (size_t)bc * LMAX;
    bool mvalid = false;
    int  nbv    = 0;
    if (lane < LMAX) {
        const int mi = bc * LMAX + lane;
        mvalid = byteMode ? (((const uint8_t*)mask)[mi] != 0)
                          : (((const int*)mask)[mi] != 0);
        nbv = nb[lane];
    }
    const unsigned long long vm = __ballot(mvalid);
    const int nv = (int)__popcll(vm);              // >= 1 (mask[:,0] always True)

    // ---- register compaction via ds_permute push ----
    // valid lane l -> rank p; invalid lane l -> nv + (#invalid below l).
    // Bijection on lanes 0..63: no collisions, every lane receives.
    const int p    = (int)__popcll(vm & ((1ull << lane) - 1ull));
    const int dsta = mvalid ? p : (nv + (lane - p));
    const int cnb  = __builtin_amdgcn_ds_permute(dsta << 2, nbv);
    // lane r (r < nv) now holds the r-th valid neighbor id in a register.

    // ---- async gather of compacted rows, chunk-XOR-rotated layout ----
    // stored 16B-chunk sc of LDS slot r holds global chunk sc ^ (r&7)
    unsigned int* buf = fwbuf[wv];
    const int sub    = lane >> 3;                  // 0..7 = slot&7 in full groups
    const int gchunk = (lane & 7) ^ sub;
    const int f      = nv >> 3;                    // full 8-row groups (uniform)
    for (int i = 0; i < f; ++i) {
        const int r = 8 * i + sub;                 // r < nv guaranteed
        const int n = __shfl(cnb, r, 64);
        const unsigned int* gp = ep16u + (size_t)n * 32 + gchunk * 4;
        __builtin_amdgcn_global_load_lds(
            (const __attribute__((address_space(1))) void*)gp,
            (__attribute__((address_space(3))) void*)&buf[i * 256],
            16, 0, 0);
    }
    // tail: width-4 pairs (2 rows / instr), slots stay <= 50
    const int t     = nv & 7;
    const int npair = (t + 1) >> 1;                // uniform, 0..4
    const int rbase = 8 * f;
    for (int p2 = 0; p2 < npair; ++p2) {
        const int r   = rbase + 2 * p2 + (lane >> 5);
        const int rc  = r < nv ? r : nv - 1;       // duplicate-fill odd tail slot
        const int n   = __shfl(cnb, rc, 64);
        const int w   = lane & 31;
        const int gwd = (((w >> 2) ^ (r & 7)) << 2) + (w & 3);
        const unsigned int* gp = ep16u + (size_t)n * 32 + gwd;
        __builtin_amdgcn_global_load_lds(
            (const __attribute__((address_space(1))) void*)gp,
            (__attribute__((address_space(3))) void*)&buf[(rbase + 2 * p2) * 32],
            4, 0, 0);
    }

    // per-wave DMA drain only — buffers are wave-private, no block barrier
    asm volatile("s_waitcnt vmcnt(0)" ::: "memory");

    // ---- phase 1: uniform k-octets, bank-uniform b128, a_src in SGPRs ----
    const int lc   = lane < nv ? lane : nv - 1;    // clamp: read a valid row
    const int rot7 = lc & 7;
    const unsigned int* fr = buf + lc * 32;
    float dot = 0.f;
#pragma unroll
    for (int k8 = 0; k8 < 8; ++k8) {
        const uint4 u = *(const uint4*)&fr[((k8 ^ rot7) << 2)];
        dot = fmaf(bflo(u.x), a_src[k8 * 8 + 0], dot);
        dot = fmaf(bfhi(u.x), a_src[k8 * 8 + 1], dot);
        dot = fmaf(bflo(u.y), a_src[k8 * 8 + 2], dot);
        dot = fmaf(bfhi(u.y), a_src[k8 * 8 + 3], dot);
        dot = fmaf(bflo(u.z), a_src[k8 * 8 + 4], dot);
        dot = fmaf(bfhi(u.z), a_src[k8 * 8 + 5], dot);
        dot = fmaf(bflo(u.w), a_src[k8 * 8 + 6], dot);
        dot = fmaf(bfhi(u.w), a_src[k8 * 8 + 7], dot);
    }
    const float lr = dot >= 0.f ? dot : 0.2f * dot;
    float s = (lane < nv) ? lr : NEG_INF;

    float mx = s;
#pragma unroll
    for (int m = 32; m >= 1; m >>= 1) mx = fmaxf(mx, __shfl_xor(mx, m, 64));
    const float e = __expf(s - mx);                // lanes >= nv -> exactly 0
    float se = e;
#pragma unroll
    for (int m = 32; m >= 1; m >>= 1) se += __shfl_xor(se, m, 64);
    const float attn = e / se;                     // lane r holds weight w_r

    // ---- phase 2: 8 rows/iter, b128 chunk-per-lane, pipelined ----
    const int s8   = lane >> 3;                    // row sub-slot 0..7
    const int gc   = lane & 7;                     // fixed col-octet (cols 8gc..+7)
    const int nit8 = (nv + 7) >> 3;                // 1..7

    float acc[8];
#pragma unroll
    for (int j = 0; j < 8; ++j) acc[j] = 0.f;

    // prefetch iteration 0
    int  rr0 = s8 < nv ? s8 : nv - 1;              // clamp (init'd slots only)
    uint4 u  = *(const uint4*)&buf[rr0 * 32 + ((gc ^ (rr0 & 7)) << 2)];
    float w  = __shfl(attn, s8, 64);               // lanes r>=nv hold attn==0

    for (int i = 0; i < nit8; ++i) {
        const int inx = (i + 1 < nit8) ? i + 1 : i;    // last iter: harmless re-read
        const int r   = 8 * inx + s8;
        const int rr  = r < nv ? r : nv - 1;
        const uint4 un = *(const uint4*)&buf[rr * 32 + ((gc ^ (rr & 7)) << 2)];
        const float wn = __shfl(attn, r, 64);          // r <= 55 < 64
        acc[0] = fmaf(w, bflo(u.x), acc[0]);
        acc[1] = fmaf(w, bfhi(u.x), acc[1]);
        acc[2] = fmaf(w, bflo(u.y), acc[2]);
        acc[3] = fmaf(w, bfhi(u.y), acc[3]);
        acc[4] = fmaf(w, bflo(u.z), acc[4]);
        acc[5] = fmaf(w, bfhi(u.z), acc[5]);
        acc[6] = fmaf(w, bflo(u.w), acc[6]);
        acc[7] = fmaf(w, bfhi(u.w), acc[7]);
        u = un; w = wn;
    }

    // reduce over the 8 lanes sharing a col-octet (lane bits 3..5)
#pragma unroll
    for (int m = 8; m <= 32; m <<= 1)
#pragma unroll
        for (int j = 0; j < 8; ++j) acc[j] += __shfl_xor(acc[j], m, 64);

    if (b < B && lane < 8) {
        float* op = out + (size_t)b * DOUT + 8 * lane;
        float4 o0; o0.x = acc[0]; o0.y = acc[1]; o0.z = acc[2]; o0.w = acc[3];
        float4 o1; o1.x = acc[4]; o1.y = acc[5]; o1.z = acc[6]; o1.w = acc[7];
        *(float4*)op       = o0;
        *(float4*)(op + 4) = o1;
    }
}

// ---------------------------------------------------------------------------
extern "C" void kernel_launch(void* const* d_in, const int* in_sizes, int n_in,
                              void* d_out, int out_size, void* d_ws, size_t ws_size,
                              hipStream_t stream)
{
    const int*   neighs  = (const int*)d_in[0];
    const void*  mask    = d_in[1];
    const float* embed   = (const float*)d_in[3];
    const float* W       = (const float*)d_in[4];
    const float* a_src   = (const float*)d_in[5];
    float* out = (float*)d_out;

    const int B = in_sizes[2];            // 50000
    const int N = in_sizes[3] / DIN;      // 200000

    unsigned short* ep16 = (unsigned short*)d_ws;   // N*64*2 = 25.6 MB

    proj_kernel<<<dim3((N + 127) / 128), dim3(256), 0, stream>>>(embed, W, ep16, N);
    agg_kernel<<<dim3((B + 3) / 4), dim3(256), 0, stream>>>(
        neighs, mask, (const unsigned int*)ep16, a_src, out, B);
}

// Round 4
// 349.223 us; speedup vs baseline: 1.0815x; 1.0237x over previous
//
#include <hip/hip_runtime.h>
#include <stdint.h>

#define DIN 256
#define DOUT 64
#define LMAX 50
#define NEG_INF -1e9f
#define WSTRIDE 264   // bf16 elems per row in LDS (padded: 2-way bank alias, free)

typedef short bf16x8 __attribute__((ext_vector_type(8)));
typedef float f32x4  __attribute__((ext_vector_type(4)));

static __device__ __forceinline__ unsigned short f2bf(float x) {
    unsigned int u = __float_as_uint(x);
    u += 0x7fffu + ((u >> 16) & 1u);     // RNE
    return (unsigned short)(u >> 16);
}
static __device__ __forceinline__ float bflo(unsigned int u) { return __uint_as_float(u << 16); }
static __device__ __forceinline__ float bfhi(unsigned int u) { return __uint_as_float(u & 0xffff0000u); }

// ---------------------------------------------------------------------------
// Kernel 1: projection via bf16 MFMA 16x16x32.
// NEW this round: A is staged through LDS ONCE with fully-coalesced float4
// loads (previously A-frags were re-read from global inside the kc-loop:
// 32KB/wave working set x 16 waves vs 32KB L1 -> thrash, ~8x re-read of
// embed from L2 plus 64-line-divergent load instructions). Block = 64 rows;
// al[64][264] bf16 (same padded stride as wl, conflict-free pattern).
// LDS 67.6KB -> 2 blocks/CU; K-loop is pure LDS + MFMA.
// ---------------------------------------------------------------------------
__global__ __launch_bounds__(256) void proj_kernel(
    const float* __restrict__ embed, const float* __restrict__ W,
    unsigned short* __restrict__ ep16, int N)
{
    __shared__ unsigned short wl[64 * WSTRIDE];   // 33,792 B
    __shared__ unsigned short al[64 * WSTRIDE];   // 33,792 B

    const int tid  = threadIdx.x;
    const int lane = tid & 63;
    const int wv   = tid >> 6;
    const int mrow = lane & 15;
    const int quad = lane >> 4;
    const int m_base = blockIdx.x * 64;

    // ---- stage W: fp32 -> bf16, layout wl[n*264 + k], coalesced ----
#pragma unroll
    for (int i = 0; i < 16; ++i) {
        const int idx4 = tid + 256 * i;          // float4 index
        const int e    = idx4 * 4;               // element = n*256 + k
        const int n    = e >> 8;
        const int k    = e & 255;
        const float4 f = *(const float4*)&W[e];
        union { unsigned short s[4]; unsigned long long v; } p;
        p.s[0] = f2bf(f.x); p.s[1] = f2bf(f.y);
        p.s[2] = f2bf(f.z); p.s[3] = f2bf(f.w);
        *(unsigned long long*)&wl[n * WSTRIDE + k] = p.v;
    }
    // ---- stage A tile: rows m_base..m_base+63, each element read ONCE ----
#pragma unroll
    for (int i = 0; i < 16; ++i) {
        const int idx4 = tid + 256 * i;
        const int e    = idx4 * 4;
        const int n    = e >> 8;                 // 0..63 tile row
        const int k    = e & 255;
        int row = m_base + n;
        if (row >= N) row = N - 1;               // clamp; store-guarded
        const float4 f = *(const float4*)&embed[(size_t)row * DIN + k];
        union { unsigned short s[4]; unsigned long long v; } p;
        p.s[0] = f2bf(f.x); p.s[1] = f2bf(f.y);
        p.s[2] = f2bf(f.z); p.s[3] = f2bf(f.w);
        *(unsigned long long*)&al[n * WSTRIDE + k] = p.v;
    }
    __syncthreads();

    // wave wv owns rows m_base + wv*16 .. +15
    f32x4 acc[4];
#pragma unroll
    for (int nt = 0; nt < 4; ++nt) acc[nt] = (f32x4){0.f, 0.f, 0.f, 0.f};

#pragma unroll
    for (int kc = 0; kc < DIN; kc += 32) {
        const bf16x8 afrag =
            *(const bf16x8*)&al[(wv * 16 + mrow) * WSTRIDE + kc + quad * 8];
#pragma unroll
        for (int nt = 0; nt < 4; ++nt) {
            const bf16x8 bfrag =
                *(const bf16x8*)&wl[(nt * 16 + mrow) * WSTRIDE + kc + quad * 8];
            acc[nt] = __builtin_amdgcn_mfma_f32_16x16x32_bf16(
                afrag, bfrag, acc[nt], 0, 0, 0);
        }
    }

#pragma unroll
    for (int nt = 0; nt < 4; ++nt)
#pragma unroll
        for (int r = 0; r < 4; ++r) {
            const int row = m_base + wv * 16 + quad * 4 + r;
            if (row < N)
                ep16[(size_t)row * DOUT + nt * 16 + mrow] = f2bf(acc[nt][r]);
        }
}

// ---------------------------------------------------------------------------
// Kernel 2: GAT attention + aggregation. UNCHANGED from round 3 (held fixed
// for attribution of the proj change).
// ---------------------------------------------------------------------------
__global__ __launch_bounds__(256, 6) void agg_kernel(
    const int* __restrict__ neighs, const void* __restrict__ mask,
    const unsigned int* __restrict__ ep16u,
    const float* __restrict__ a_src,
    float* __restrict__ out, int B)
{
    __shared__ unsigned int fwbuf[4][LMAX * 32];   // 25,600 B -> 6 blocks/CU

    const int tid  = threadIdx.x;
    const int lane = tid & 63;
    const int wv   = tid >> 6;
    const int b    = blockIdx.x * 4 + wv;
    const int bc   = b < B ? b : B - 1;            // clamp (grid exact for B=50000)

    // mask storage-format detection: flat element 50 (row1,col0) always True.
    const unsigned int* mw = (const unsigned int*)mask;
    const bool byteMode = (mw[12] > 1u);

    // per-lane neighbor mask (lane = l) + neighbor id
    const int* nb = neighs + (size_t)bc * LMAX;
    bool mvalid = false;
    int  nbv    = 0;
    if (lane < LMAX) {
        const int mi = bc * LMAX + lane;
        mvalid = byteMode ? (((const uint8_t*)mask)[mi] != 0)
                          : (((const int*)mask)[mi] != 0);
        nbv = nb[lane];
    }
    const unsigned long long vm = __ballot(mvalid);
    const int nv = (int)__popcll(vm);              // >= 1 (mask[:,0] always True)

    // ---- register compaction via ds_permute push ----
    const int p    = (int)__popcll(vm & ((1ull << lane) - 1ull));
    const int dsta = mvalid ? p : (nv + (lane - p));
    const int cnb  = __builtin_amdgcn_ds_permute(dsta << 2, nbv);
    // lane r (r < nv) now holds the r-th valid neighbor id in a register.

    // ---- async gather of compacted rows, chunk-XOR-rotated layout ----
    unsigned int* buf = fwbuf[wv];
    const int sub    = lane >> 3;                  // 0..7 = slot&7 in full groups
    const int gchunk = (lane & 7) ^ sub;
    const int f      = nv >> 3;                    // full 8-row groups (uniform)
    for (int i = 0; i < f; ++i) {
        const int r = 8 * i + sub;                 // r < nv guaranteed
        const int n = __shfl(cnb, r, 64);
        const unsigned int* gp = ep16u + (size_t)n * 32 + gchunk * 4;
        __builtin_amdgcn_global_load_lds(
            (const __attribute__((address_space(1))) void*)gp,
            (__attribute__((address_space(3))) void*)&buf[i * 256],
            16, 0, 0);
    }
    // tail: width-4 pairs (2 rows / instr), slots stay <= 50
    const int t     = nv & 7;
    const int npair = (t + 1) >> 1;                // uniform, 0..4
    const int rbase = 8 * f;
    for (int p2 = 0; p2 < npair; ++p2) {
        const int r   = rbase + 2 * p2 + (lane >> 5);
        const int rc  = r < nv ? r : nv - 1;       // duplicate-fill odd tail slot
        const int n   = __shfl(cnb, rc, 64);
        const int w   = lane & 31;
        const int gwd = (((w >> 2) ^ (r & 7)) << 2) + (w & 3);
        const unsigned int* gp = ep16u + (size_t)n * 32 + gwd;
        __builtin_amdgcn_global_load_lds(
            (const __attribute__((address_space(1))) void*)gp,
            (__attribute__((address_space(3))) void*)&buf[(rbase + 2 * p2) * 32],
            4, 0, 0);
    }

    // per-wave DMA drain only — buffers are wave-private, no block barrier
    asm volatile("s_waitcnt vmcnt(0)" ::: "memory");

    // ---- phase 1: uniform k-octets, bank-uniform b128, a_src in SGPRs ----
    const int lc   = lane < nv ? lane : nv - 1;    // clamp: read a valid row
    const int rot7 = lc & 7;
    const unsigned int* fr = buf + lc * 32;
    float dot = 0.f;
#pragma unroll
    for (int k8 = 0; k8 < 8; ++k8) {
        const uint4 u = *(const uint4*)&fr[((k8 ^ rot7) << 2)];
        dot = fmaf(bflo(u.x), a_src[k8 * 8 + 0], dot);
        dot = fmaf(bfhi(u.x), a_src[k8 * 8 + 1], dot);
        dot = fmaf(bflo(u.y), a_src[k8 * 8 + 2], dot);
        dot = fmaf(bfhi(u.y), a_src[k8 * 8 + 3], dot);
        dot = fmaf(bflo(u.z), a_src[k8 * 8 + 4], dot);
        dot = fmaf(bfhi(u.z), a_src[k8 * 8 + 5], dot);
        dot = fmaf(bflo(u.w), a_src[k8 * 8 + 6], dot);
        dot = fmaf(bfhi(u.w), a_src[k8 * 8 + 7], dot);
    }
    const float lr = dot >= 0.f ? dot : 0.2f * dot;
    float s = (lane < nv) ? lr : NEG_INF;

    float mx = s;
#pragma unroll
    for (int m = 32; m >= 1; m >>= 1) mx = fmaxf(mx, __shfl_xor(mx, m, 64));
    const float e = __expf(s - mx);                // lanes >= nv -> exactly 0
    float se = e;
#pragma unroll
    for (int m = 32; m >= 1; m >>= 1) se += __shfl_xor(se, m, 64);
    const float attn = e / se;                     // lane r holds weight w_r

    // ---- phase 2: 8 rows/iter, b128 chunk-per-lane, pipelined ----
    const int s8   = lane >> 3;                    // row sub-slot 0..7
    const int gc   = lane & 7;                     // fixed col-octet (cols 8gc..+7)
    const int nit8 = (nv + 7) >> 3;                // 1..7

    float acc[8];
#pragma unroll
    for (int j = 0; j < 8; ++j) acc[j] = 0.f;

    // prefetch iteration 0
    int  rr0 = s8 < nv ? s8 : nv - 1;              // clamp (init'd slots only)
    uint4 u  = *(const uint4*)&buf[rr0 * 32 + ((gc ^ (rr0 & 7)) << 2)];
    float w  = __shfl(attn, s8, 64);               // lanes r>=nv hold attn==0

    for (int i = 0; i < nit8; ++i) {
        const int inx = (i + 1 < nit8) ? i + 1 : i;    // last iter: harmless re-read
        const int r   = 8 * inx + s8;
        const int rr  = r < nv ? r : nv - 1;
        const uint4 un = *(const uint4*)&buf[rr * 32 + ((gc ^ (rr & 7)) << 2)];
        const float wn = __shfl(attn, r, 64);          // r <= 55 < 64
        acc[0] = fmaf(w, bflo(u.x), acc[0]);
        acc[1] = fmaf(w, bfhi(u.x), acc[1]);
        acc[2] = fmaf(w, bflo(u.y), acc[2]);
        acc[3] = fmaf(w, bfhi(u.y), acc[3]);
        acc[4] = fmaf(w, bflo(u.z), acc[4]);
        acc[5] = fmaf(w, bfhi(u.z), acc[5]);
        acc[6] = fmaf(w, bflo(u.w), acc[6]);
        acc[7] = fmaf(w, bfhi(u.w), acc[7]);
        u = un; w = wn;
    }

    // reduce over the 8 lanes sharing a col-octet (lane bits 3..5)
#pragma unroll
    for (int m = 8; m <= 32; m <<= 1)
#pragma unroll
        for (int j = 0; j < 8; ++j) acc[j] += __shfl_xor(acc[j], m, 64);

    if (b < B && lane < 8) {
        float* op = out + (size_t)b * DOUT + 8 * lane;
        float4 o0; o0.x = acc[0]; o0.y = acc[1]; o0.z = acc[2]; o0.w = acc[3];
        float4 o1; o1.x = acc[4]; o1.y = acc[5]; o1.z = acc[6]; o1.w = acc[7];
        *(float4*)op       = o0;
        *(float4*)(op + 4) = o1;
    }
}

// ---------------------------------------------------------------------------
extern "C" void kernel_launch(void* const* d_in, const int* in_sizes, int n_in,
                              void* d_out, int out_size, void* d_ws, size_t ws_size,
                              hipStream_t stream)
{
    const int*   neighs  = (const int*)d_in[0];
    const void*  mask    = d_in[1];
    const float* embed   = (const float*)d_in[3];
    const float* W       = (const float*)d_in[4];
    const float* a_src   = (const float*)d_in[5];
    float* out = (float*)d_out;

    const int B = in_sizes[2];            // 50000
    const int N = in_sizes[3] / DIN;      // 200000

    unsigned short* ep16 = (unsigned short*)d_ws;   // N*64*2 = 25.6 MB

    proj_kernel<<<dim3((N + 63) / 64), dim3(256), 0, stream>>>(embed, W, ep16, N);
    agg_kernel<<<dim3((B + 3) / 4), dim3(256), 0, stream>>>(
        neighs, mask, (const unsigned int*)ep16, a_src, out, B);
}